// Round 7
// baseline (751.508 us; speedup 1.0000x reference)
//
#include <hip/hip_runtime.h>
#include <hip/hip_bf16.h>
#include <math.h>

typedef __hip_bfloat16 bf16;
using short8 = __attribute__((ext_vector_type(8))) short;
using f32x4  = __attribute__((ext_vector_type(4))) float;

#define B_    4
#define NQ_   512
#define NC_   2048
#define DQ_   1024
#define DC_   768
#define C_    1024
#define H_    16
#define HD_   64
#define EPS_  1e-5f

// ---- runtime-dtyped load of EXTERNAL tensors (flag: 1=fp32, 0=bf16) ----
__device__ __forceinline__ float ldin(const void* p, size_t i, int f32) {
    return f32 ? ((const float*)p)[i]
               : __bfloat162float(((const bf16*)p)[i]);
}
__device__ __forceinline__ unsigned bfb(float f) {
    return (unsigned)__builtin_bit_cast(unsigned short, __float2bfloat16(f));
}

// async global->LDS, 16B per lane; LDS dest = wave-uniform base + lane*16
typedef const __attribute__((address_space(1))) unsigned int ga_u32;
typedef __attribute__((address_space(3))) unsigned int ls_u32;
__device__ __forceinline__ void gl16(const void* g, void* l) {
    __builtin_amdgcn_global_load_lds((ga_u32*)g, (ls_u32*)l, 16, 0, 0);
}

// ---------------------------------------------------------------------------
// dtype sniffer: flag[0] = (fp32 ? 1 : 0).
// ---------------------------------------------------------------------------
__global__ __launch_bounds__(256)
void sniff_k(const void* __restrict__ q, int* __restrict__ flag)
{
    __shared__ int red[256];
    const unsigned* w = (const unsigned*)q;
    const int t = threadIdx.x;
    int cnt = 0;
    for (int i = t; i < 1024; i += 256) {
        unsigned e = (w[i] >> 7) & 0xFFu;
        cnt += (e >= 0x70u && e <= 0x82u) ? 1 : 0;
    }
    red[t] = cnt; __syncthreads();
    for (int s = 128; s > 0; s >>= 1) { if (t < s) red[t] += red[t + s]; __syncthreads(); }
    if (t == 0) flag[0] = (red[0] > 512) ? 0 : 1;
}

// ---------------------------------------------------------------------------
// bf16 conversion (or copy) of external tensors; 8 elems/thread.
// ---------------------------------------------------------------------------
__global__ __launch_bounds__(256)
void cvt_k(const void* __restrict__ src, bf16* __restrict__ dst, int n8,
           const int* __restrict__ dtf)
{
    const int i = blockIdx.x * 256 + threadIdx.x;
    if (i >= n8) return;
    if (dtf[0]) {
        const float* s = (const float*)src + (size_t)i * 8;
        float4 a = *(const float4*)s, b = *(const float4*)(s + 4);
        uint4 o;
        o.x = bfb(a.x) | (bfb(a.y) << 16);
        o.y = bfb(a.z) | (bfb(a.w) << 16);
        o.z = bfb(b.x) | (bfb(b.y) << 16);
        o.w = bfb(b.z) | (bfb(b.w) << 16);
        *(uint4*)(dst + (size_t)i * 8) = o;
    } else {
        *(uint4*)(dst + (size_t)i * 8) = *(const uint4*)((const bf16*)src + (size_t)i * 8);
    }
}

// ---------------------------------------------------------------------------
// Batched transpose: for each job, dst[N][K] bf16 = src[off + k*ld + n]
// (runtime dtype). One launch handles up to 6 jobs via a tile table.
// ---------------------------------------------------------------------------
struct KTr {
    const void* src[6];
    bf16*       dst[6];
    long long   off[6];
    int ld[6], K[6], N[6];
    int start[7];
    int njobs;
};

__global__ __launch_bounds__(256)
void tr_all(KTr J, const int* __restrict__ dtf)
{
    __shared__ short T[64 * 65];
    const int f32 = dtf[0];
    const int t = threadIdx.x;
    int bid = blockIdx.x, j = 0;
    while (j + 1 < J.njobs && bid >= J.start[j + 1]) ++j;
    const int tt = bid - J.start[j];
    const int nx = J.N[j] >> 6;
    const int n0 = (tt % nx) * 64, k0 = (tt / nx) * 64;
    const int ld = J.ld[j], K = J.K[j];
    {
        const int k = t >> 2, nq = (t & 3) * 16;
        size_t si = (size_t)J.off[j] + (size_t)(k0 + k) * ld + n0 + nq;
        short v[16];
        if (f32) {
            const float* s = (const float*)J.src[j] + si;
#pragma unroll
            for (int u = 0; u < 4; u++) {
                float4 f = *(const float4*)(s + u * 4);
                v[u*4+0] = (short)bfb(f.x); v[u*4+1] = (short)bfb(f.y);
                v[u*4+2] = (short)bfb(f.z); v[u*4+3] = (short)bfb(f.w);
            }
        } else {
            const bf16* s = (const bf16*)J.src[j] + si;
#pragma unroll
            for (int u = 0; u < 2; u++) {
                uint4 x = *(const uint4*)(s + u * 8);
                unsigned a[4] = {x.x, x.y, x.z, x.w};
#pragma unroll
                for (int m = 0; m < 4; m++) {
                    v[u*8 + m*2]     = (short)(a[m] & 0xffffu);
                    v[u*8 + m*2 + 1] = (short)(a[m] >> 16);
                }
            }
        }
#pragma unroll
        for (int jj = 0; jj < 16; jj++) T[k * 65 + nq + jj] = v[jj];
    }
    __syncthreads();
    {
        const int n = t >> 2, kq = (t & 3) * 16;
        unsigned pk[8];
#pragma unroll
        for (int u = 0; u < 8; u++) {
            unsigned lo = (unsigned short)T[(kq + u*2)     * 65 + n];
            unsigned hi = (unsigned short)T[(kq + u*2 + 1) * 65 + n];
            pk[u] = lo | (hi << 16);
        }
        bf16* d = J.dst[j] + (size_t)(n0 + n) * K + k0 + kq;
        *(uint4*)(d)     = make_uint4(pk[0], pk[1], pk[2], pk[3]);
        *(uint4*)(d + 8) = make_uint4(pk[4], pk[5], pk[6], pk[7]);
    }
}

// ---------------------------------------------------------------------------
// Fast bf16 GEMM: out[M,N] = act(A[M,K] @ Wt[N,K]^T + bscale*bias) (+= if ACC)
// global_load_lds 16B staging (XOR-swizzled), double-buffered, 2-phase.
// Tiles: <128,128,BK32> (4x4), <128,64,BK32> (2x4), <64,64,BK64> (2x2, 8
// MFMA/barrier — halves barrier-drain cost for the N=1024 fleet).
// BK64 swizzle: LDS slot (row,c) holds global chunk c^(row&7); reader XORs
// with (lm&7) -> 8 distinct 4-bank spans = conflict-free at the b128 floor.
// XCD-bijective block swizzle (grid always a multiple of 8 blocks).
// ---------------------------------------------------------------------------
template<int ACT, int ACC, int OUTF32, int BM, int BN, int BK>
__global__ __launch_bounds__(256)
void gemm_bf(const bf16* __restrict__ A, int lda,
             const bf16* __restrict__ Wt,
             const void* __restrict__ bias, size_t boff, float bscale,
             void* __restrict__ outp, int M, int N, int K,
             const int* __restrict__ dtf)
{
    __shared__ short As[2][BM * BK];
    __shared__ short Bs[2][BN * BK];
    constexpr int MI = (BM == 128 && BN == 128) ? 4 : 2;
    constexpr int NJ = (BM == 64) ? 2 : 4;
    const int t  = threadIdx.x;
    const int nwg = gridDim.x * gridDim.y;
    int flat = blockIdx.y * gridDim.x + blockIdx.x;
    flat = (flat & 7) * (nwg >> 3) + (flat >> 3);
    const int row0 = (flat / gridDim.x) * BM, col0 = (flat % gridDim.x) * BN;
    const int wv = t >> 6, l = t & 63;
    const int lm = l & 15, lq = l >> 4;
    // BK32 staging coords (4 chunks/row of 32 shorts)
    const int lr = l >> 2, lc = l & 3;
    const int swc  = lc ^ ((lr >> 1) & 3);
    const int koff = (lq ^ ((lm >> 1) & 3)) << 3;
    // BK64 staging coords (8 chunks/row of 64 shorts)
    const int lr8 = l >> 3, lc8 = l & 7;
    const int swc8 = lc8 ^ (lr8 & 7);
    const int wr = (BM == 128 && BN == 128) ? (wv >> 1) * 64
                 : (BM == 128) ? wv * 32 : (wv >> 1) * 32;
    const int wc = (BN == 128) ? (wv & 1) * 64
                 : (BM == 128) ? 0 : (wv & 1) * 32;

    const bf16* Ag0; const bf16* Ag1; const bf16* Bg0; const bf16* Bg1;
    if constexpr (BK == 64) {
        Ag0 = A + (size_t)(row0 + wv * 16 + lr8) * lda + swc8 * 8;
        Ag1 = Ag0 + (size_t)8 * lda;
        Bg0 = Wt + (size_t)(col0 + wv * 16 + lr8) * K + swc8 * 8;
        Bg1 = Bg0 + (size_t)8 * K;
    } else {
        Ag0 = A + (size_t)(row0 + ((BM == 128) ? wv * 32 : wv * 16) + lr) * lda + swc * 8;
        Ag1 = Ag0 + (size_t)16 * lda;
        Bg0 = Wt + (size_t)(col0 + ((BN == 128) ? wv * 32 : wv * 16) + lr) * K + swc * 8;
        Bg1 = Bg0 + (size_t)16 * K;
    }

    f32x4 acc[MI][NJ];
#pragma unroll
    for (int i = 0; i < MI; i++)
#pragma unroll
        for (int j = 0; j < NJ; j++) { acc[i][j][0]=0.f; acc[i][j][1]=0.f; acc[i][j][2]=0.f; acc[i][j][3]=0.f; }

    auto stage = [&](int b, int k0) {
        if constexpr (BK == 64) {
            gl16(Ag0 + k0, &As[b][(wv * 16) * 64]);
            gl16(Ag1 + k0, &As[b][(wv * 16 + 8) * 64]);
            gl16(Bg0 + k0, &Bs[b][(wv * 16) * 64]);
            gl16(Bg1 + k0, &Bs[b][(wv * 16 + 8) * 64]);
        } else {
            if constexpr (BM == 128) {
                gl16(Ag0 + k0, &As[b][(wv * 32) * 32]);
                gl16(Ag1 + k0, &As[b][(wv * 32 + 16) * 32]);
            } else {
                gl16(Ag0 + k0, &As[b][(wv * 16) * 32]);
            }
            if constexpr (BN == 128) {
                gl16(Bg0 + k0, &Bs[b][(wv * 32) * 32]);
                gl16(Bg1 + k0, &Bs[b][(wv * 32 + 16) * 32]);
            } else {
                gl16(Bg0 + k0, &Bs[b][(wv * 16) * 32]);
            }
        }
    };

    const int nt = K / BK;
    stage(0, 0);
    __syncthreads();
    int cur = 0;
    for (int tt = 0; tt < nt; ++tt) {
        if (tt + 1 < nt) stage(cur ^ 1, (tt + 1) * BK);
        if constexpr (BK == 64) {
#pragma unroll
            for (int kk = 0; kk < 2; kk++) {
                short8 af[MI], bfr[NJ];
#pragma unroll
                for (int i = 0; i < MI; i++)
                    af[i]  = *(const short8*)&As[cur][(wr + i*16 + lm) * 64 + (((kk << 2) | lq) ^ (lm & 7)) * 8];
#pragma unroll
                for (int j = 0; j < NJ; j++)
                    bfr[j] = *(const short8*)&Bs[cur][(wc + j*16 + lm) * 64 + (((kk << 2) | lq) ^ (lm & 7)) * 8];
#pragma unroll
                for (int i = 0; i < MI; i++)
#pragma unroll
                    for (int j = 0; j < NJ; j++)
                        acc[i][j] = __builtin_amdgcn_mfma_f32_16x16x32_bf16(af[i], bfr[j], acc[i][j], 0, 0, 0);
            }
        } else {
            short8 af[MI], bfr[NJ];
#pragma unroll
            for (int i = 0; i < MI; i++) af[i]  = *(const short8*)&As[cur][(wr + i*16 + lm) * 32 + koff];
#pragma unroll
            for (int j = 0; j < NJ; j++) bfr[j] = *(const short8*)&Bs[cur][(wc + j*16 + lm) * 32 + koff];
#pragma unroll
            for (int i = 0; i < MI; i++)
#pragma unroll
                for (int j = 0; j < NJ; j++)
                    acc[i][j] = __builtin_amdgcn_mfma_f32_16x16x32_bf16(af[i], bfr[j], acc[i][j], 0, 0, 0);
        }
        __syncthreads();
        cur ^= 1;
    }

    const int fb = dtf[0];
#pragma unroll
    for (int i = 0; i < MI; i++) {
#pragma unroll
        for (int j = 0; j < NJ; j++) {
            const int cgl = col0 + wc + j * 16 + lm;
            const float bsv = bscale * ldin(bias, boff + cgl, fb);
#pragma unroll
            for (int r = 0; r < 4; r++) {
                const int rgl = row0 + wr + i * 16 + lq * 4 + r;
                float v = acc[i][j][r] + bsv;
                if (ACT == 1) v = 0.5f * v * (1.0f + erff(v * 0.70710678118654752440f));
                size_t o = (size_t)rgl * N + cgl;
                if constexpr (ACC)          ((float*)outp)[o] += v;
                else if constexpr (OUTF32)  ((float*)outp)[o] = v;
                else                        ((bf16*)outp)[o] = __float2bfloat16(v);
            }
        }
    }
}

// ---------------------------------------------------------------------------
// KV GEMM: A[M,K] @ Wt[2C,K]^T + bkv. K-half cols (<C) written row-major to
// kb[b][key][C]; V-half cols transposed in LDS and written to vt[b][d][NC].
// ---------------------------------------------------------------------------
__global__ __launch_bounds__(256)
void gemm_kv(const bf16* __restrict__ A, int lda,
             const bf16* __restrict__ Wt,
             const void* __restrict__ bias, size_t boff,
             bf16* __restrict__ kb, bf16* __restrict__ vt,
             int M, int K, const int* __restrict__ dtf)
{
    __shared__ short smem[17408];          // 34816 B
    const int t  = threadIdx.x;
    const int nwg = gridDim.x * gridDim.y;
    int flat = blockIdx.y * gridDim.x + blockIdx.x;
    flat = (flat & 7) * (nwg >> 3) + (flat >> 3);
    const int row0 = (flat / gridDim.x) * 128, col0 = (flat % gridDim.x) * 128;
    const int wv = t >> 6, l = t & 63;
    const int lm = l & 15, lq = l >> 4;
    const int lr = l >> 2, lc = l & 3;
    const int swc  = lc ^ ((lr >> 1) & 3);
    const int koff = (lq ^ ((lm >> 1) & 3)) << 3;
    const int wr = (wv >> 1) * 64, wc = (wv & 1) * 64;

    const bf16* Ag0 = A + (size_t)(row0 + wv * 32 + lr) * lda + swc * 8;
    const bf16* Ag1 = Ag0 + (size_t)16 * lda;
    const bf16* Bg0 = Wt + (size_t)(col0 + wv * 32 + lr) * K + swc * 8;
    const bf16* Bg1 = Bg0 + (size_t)16 * K;

    f32x4 acc[4][4];
#pragma unroll
    for (int i = 0; i < 4; i++)
#pragma unroll
        for (int j = 0; j < 4; j++) { acc[i][j][0]=0.f; acc[i][j][1]=0.f; acc[i][j][2]=0.f; acc[i][j][3]=0.f; }

    auto stage = [&](int b, int k0) {
        gl16(Ag0 + k0, &smem[b * 4096 + (wv * 32) * 32]);
        gl16(Ag1 + k0, &smem[b * 4096 + (wv * 32 + 16) * 32]);
        gl16(Bg0 + k0, &smem[8192 + b * 4096 + (wv * 32) * 32]);
        gl16(Bg1 + k0, &smem[8192 + b * 4096 + (wv * 32 + 16) * 32]);
    };

    const int nt = K >> 5;
    stage(0, 0);
    __syncthreads();
    int cur = 0;
    for (int tt = 0; tt < nt; ++tt) {
        if (tt + 1 < nt) stage(cur ^ 1, (tt + 1) * 32);
        short8 af[4], bfr[4];
#pragma unroll
        for (int i = 0; i < 4; i++) af[i]  = *(const short8*)&smem[cur * 4096 + (wr + i*16 + lm) * 32 + koff];
#pragma unroll
        for (int j = 0; j < 4; j++) bfr[j] = *(const short8*)&smem[8192 + cur * 4096 + (wc + j*16 + lm) * 32 + koff];
#pragma unroll
        for (int i = 0; i < 4; i++)
#pragma unroll
            for (int j = 0; j < 4; j++)
                acc[i][j] = __builtin_amdgcn_mfma_f32_16x16x32_bf16(af[i], bfr[j], acc[i][j], 0, 0, 0);
        __syncthreads();
        cur ^= 1;
    }

    const int fb = dtf[0];
    if (col0 < C_) {
#pragma unroll
        for (int i = 0; i < 4; i++)
#pragma unroll
            for (int j = 0; j < 4; j++) {
                const int cgl = col0 + wc + j * 16 + lm;
                const float bsv = ldin(bias, boff + cgl, fb);
#pragma unroll
                for (int r = 0; r < 4; r++) {
                    const int rgl = row0 + wr + i * 16 + lq * 4 + r;
                    kb[(size_t)rgl * C_ + cgl] = __float2bfloat16(acc[i][j][r] + bsv);
                }
            }
    } else {
#pragma unroll
        for (int i = 0; i < 4; i++)
#pragma unroll
            for (int j = 0; j < 4; j++) {
                const int cl = wc + j * 16 + lm;
                const float bsv = ldin(bias, boff + col0 + cl, fb);
                unsigned p0 = bfb(acc[i][j][0] + bsv) | (bfb(acc[i][j][1] + bsv) << 16);
                unsigned p1 = bfb(acc[i][j][2] + bsv) | (bfb(acc[i][j][3] + bsv) << 16);
                *(uint2*)&smem[cl * 136 + wr + i * 16 + lq * 4] = make_uint2(p0, p1);
            }
        __syncthreads();
        const int dr = t >> 1, half = (t & 1) * 64;
        const int b = row0 >> 11, key0 = row0 & (NC_ - 1);
        bf16* dst = vt + (size_t)b * C_ * NC_ + (size_t)(col0 - C_ + dr) * NC_ + key0 + half;
#pragma unroll
        for (int u = 0; u < 8; u++)
            *(uint4*)(dst + u * 8) = *(const uint4*)&smem[dr * 136 + half + u * 8];
    }
}

// ---------------------------------------------------------------------------
// LayerNorm (C_=1024).
// ---------------------------------------------------------------------------
template<int OFINAL>
__global__ __launch_bounds__(256)
void ln_k(const float* __restrict__ x, const void* __restrict__ g,
          const void* __restrict__ b, size_t gboff, void* __restrict__ out,
          const int* __restrict__ dtf)
{
    __shared__ float red[256];
    const int f32 = dtf[0];
    const int row = blockIdx.x;
    const int t = threadIdx.x;
    const float* xr = x + (size_t)row * C_;
    float v[4];
#pragma unroll
    for (int i = 0; i < 4; i++) v[i] = xr[t + 256 * i];
    float s = v[0] + v[1] + v[2] + v[3];
    red[t] = s; __syncthreads();
    for (int st = 128; st > 0; st >>= 1) { if (t < st) red[t] += red[t + st]; __syncthreads(); }
    float mean = red[0] * (1.0f / C_);
    __syncthreads();
    float s2 = 0.f;
#pragma unroll
    for (int i = 0; i < 4; i++) { float d = v[i] - mean; s2 += d * d; }
    red[t] = s2; __syncthreads();
    for (int st = 128; st > 0; st >>= 1) { if (t < st) red[t] += red[t + st]; __syncthreads(); }
    float rstd = rsqrtf(red[0] * (1.0f / C_) + EPS_);
#pragma unroll
    for (int i = 0; i < 4; i++) {
        int cc = t + 256 * i;
        float r = (v[i] - mean) * rstd * ldin(g, gboff + cc, f32) + ldin(b, gboff + cc, f32);
        size_t o = (size_t)row * C_ + cc;
        if constexpr (OFINAL) {
            if (f32) ((float*)out)[o] = r; else ((bf16*)out)[o] = __float2bfloat16(r);
        } else {
            ((bf16*)out)[o] = __float2bfloat16(r);
        }
    }
}

// ---------------------------------------------------------------------------
// MFMA flash attention, KVBLK=128. 256 thr = 4 waves; wave owns 16 q-rows.
// Mask folded as additive bias (fmaf), defer-max rescale (THR=8), P stride
// 140 (2-way bank = free). NSPLIT=2 writes unnormalized partials + merge.
// ---------------------------------------------------------------------------
template<int NSPLIT>
__global__ __launch_bounds__(256)
void attn_mfma(const bf16* __restrict__ qh, const bf16* __restrict__ kb,
               const bf16* __restrict__ vt, const int* __restrict__ mask,
               bf16* __restrict__ out,
               float* __restrict__ po, float* __restrict__ pm,
               float* __restrict__ pl)
{
    __shared__ short Ks[128 * 72];     // [key][d]
    __shared__ short Vs[64 * 136];     // [d][key]
    __shared__ short Ps[4][16 * 140];  // per-wave P [q][key], stride 140

    const int id = blockIdx.x;
    const int xcd = id & 7, kk = id >> 3;
    const int p = xcd + ((kk >> 3) << 3);
    int bb, h, sp;
    if constexpr (NSPLIT == 2) { bb = p >> 5; h = (p >> 1) & 15; sp = p & 1; }
    else                       { bb = p >> 4; h = p & 15;        sp = 0;     }
    const int q0 = (kk & 7) * 64;
    const int kbase = sp * (NC_ / NSPLIT);
    const int klen  = NC_ / NSPLIT;

    const bf16* qhb = qh + (size_t)bb * NQ_ * C_;
    const bf16* kbb = kb + (size_t)bb * NC_ * C_;
    const bf16* vtb = vt + (size_t)bb * C_ * NC_ + (size_t)h * HD_ * NC_;
    const int*  mb  = mask + bb * NC_ + kbase;
    bf16* ob = out + (size_t)bb * NQ_ * C_;

    const int t  = threadIdx.x;
    const int w  = t >> 6, l = t & 63;
    const int lm = l & 15, lq = l >> 4;
    short* Pw = Ps[w];

    short8 qf[2];
    {
        const bf16* qp = qhb + (size_t)(q0 + w * 16 + lm) * C_ + h * HD_ + lq * 8;
        qf[0] = *(const short8*)(qp);
        qf[1] = *(const short8*)(qp + 32);
    }

    f32x4 o[4];
#pragma unroll
    for (int jd = 0; jd < 4; jd++) { o[jd][0]=0.f; o[jd][1]=0.f; o[jd][2]=0.f; o[jd][3]=0.f; }
    float m_run[4], l_run[4];
#pragma unroll
    for (int r = 0; r < 4; r++) { m_run[r] = -1e30f; l_run[r] = 0.f; }

    const int kr4 = t >> 2;                    // 0..63
    const int c16 = (t & 3) * 16;              // K col chunk (shorts)
    const int c32 = (t & 3) * 32;              // V key chunk (shorts)
    const bf16* kg = kbb + (size_t)(kbase + kr4) * C_ + h * HD_ + c16;
    const bf16* vg = vtb + (size_t)kr4 * NC_ + kbase + c32;

    uint4 k00, k01, k10, k11, v0, v1, v2, v3;
    int mk[8];
    {
        k00 = *(const uint4*)(kg);
        k01 = *(const uint4*)(kg + 8);
        k10 = *(const uint4*)(kg + (size_t)64 * C_);
        k11 = *(const uint4*)(kg + (size_t)64 * C_ + 8);
        v0  = *(const uint4*)(vg);
        v1  = *(const uint4*)(vg + 8);
        v2  = *(const uint4*)(vg + 16);
        v3  = *(const uint4*)(vg + 24);
#pragma unroll
        for (int jt = 0; jt < 8; jt++) mk[jt] = mb[jt * 16 + lm];
    }

    for (int k0 = 0; k0 < klen; k0 += 128) {
        __syncthreads();   // previous tile's LDS reads complete
        *(uint4*)&Ks[kr4 * 72 + c16]            = k00;
        *(uint4*)&Ks[kr4 * 72 + c16 + 8]        = k01;
        *(uint4*)&Ks[(kr4 + 64) * 72 + c16]     = k10;
        *(uint4*)&Ks[(kr4 + 64) * 72 + c16 + 8] = k11;
        *(uint4*)&Vs[kr4 * 136 + c32]      = v0;
        *(uint4*)&Vs[kr4 * 136 + c32 + 8]  = v1;
        *(uint4*)&Vs[kr4 * 136 + c32 + 16] = v2;
        *(uint4*)&Vs[kr4 * 136 + c32 + 24] = v3;
        float fbias[8];
#pragma unroll
        for (int jt = 0; jt < 8; jt++) fbias[jt] = mk[jt] ? 0.f : -1e30f;
        __syncthreads();

        if (k0 + 128 < klen) {
            const bf16* kp = kg + (size_t)(k0 + 128) * C_;
            k00 = *(const uint4*)(kp);
            k01 = *(const uint4*)(kp + 8);
            k10 = *(const uint4*)(kp + (size_t)64 * C_);
            k11 = *(const uint4*)(kp + (size_t)64 * C_ + 8);
            const bf16* vp = vg + k0 + 128;
            v0 = *(const uint4*)(vp);
            v1 = *(const uint4*)(vp + 8);
            v2 = *(const uint4*)(vp + 16);
            v3 = *(const uint4*)(vp + 24);
#pragma unroll
            for (int jt = 0; jt < 8; jt++) mk[jt] = mb[k0 + 128 + jt * 16 + lm];
        }

        // S = Q @ K^T : 8 key-tiles x 2 d-chunks
        f32x4 s[8];
#pragma unroll
        for (int jt = 0; jt < 8; jt++) { s[jt][0]=0.f; s[jt][1]=0.f; s[jt][2]=0.f; s[jt][3]=0.f; }
        __builtin_amdgcn_s_setprio(1);
#pragma unroll
        for (int dc = 0; dc < 2; dc++) {
#pragma unroll
            for (int jt = 0; jt < 8; jt++) {
                short8 kf = *(const short8*)&Ks[(jt * 16 + lm) * 72 + dc * 32 + lq * 8];
                s[jt] = __builtin_amdgcn_mfma_f32_16x16x32_bf16(qf[dc], kf, s[jt], 0, 0, 0);
            }
        }
        __builtin_amdgcn_s_setprio(0);
#pragma unroll
        for (int jt = 0; jt < 8; jt++) {
#pragma unroll
            for (int r = 0; r < 4; r++)
                s[jt][r] = fmaf(s[jt][r], 0.125f, fbias[jt]);
        }

        // online softmax per row (16-lane row groups); defer-max THR=8
#pragma unroll
        for (int r = 0; r < 4; r++) {
            float mt = fmaxf(fmaxf(fmaxf(s[0][r], s[1][r]), fmaxf(s[2][r], s[3][r])),
                             fmaxf(fmaxf(s[4][r], s[5][r]), fmaxf(s[6][r], s[7][r])));
#pragma unroll
            for (int sh = 1; sh < 16; sh <<= 1) mt = fmaxf(mt, __shfl_xor(mt, sh, 64));
            const bool up = mt > m_run[r] + 8.f;      // uniform in 16-lane group
            const float nm = up ? mt : m_run[r];
            float rs = 0.f;
            short* pr = &Pw[(lq * 4 + r) * 140 + lm];
#pragma unroll
            for (int jt = 0; jt < 8; jt++) {
                float pv = __expf(s[jt][r] - nm);
                pr[jt * 16] = (short)bfb(pv);
                rs += pv;
            }
#pragma unroll
            for (int sh = 1; sh < 16; sh <<= 1) rs += __shfl_xor(rs, sh, 64);
            if (up) {
                const float al = __expf(m_run[r] - nm);
                l_run[r] = l_run[r] * al + rs;
                m_run[r] = mt;
#pragma unroll
                for (int jd = 0; jd < 4; jd++) o[jd][r] *= al;
            } else {
                l_run[r] += rs;
            }
        }

        // PV: A = P[q][key] (per-wave LDS), B = V^T[d][key]
        short8 pa[4];
#pragma unroll
        for (int c = 0; c < 4; c++) pa[c] = *(const short8*)&Pw[lm * 140 + c * 32 + lq * 8];
        __builtin_amdgcn_s_setprio(1);
#pragma unroll
        for (int jd = 0; jd < 4; jd++) {
#pragma unroll
            for (int c = 0; c < 4; c++) {
                short8 vf = *(const short8*)&Vs[(jd * 16 + lm) * 136 + c * 32 + lq * 8];
                o[jd] = __builtin_amdgcn_mfma_f32_16x16x32_bf16(pa[c], vf, o[jd], 0, 0, 0);
            }
        }
        __builtin_amdgcn_s_setprio(0);
    }

    if constexpr (NSPLIT == 2) {
        const int pidx = ((bb * 16 + h) * 2 + sp);
#pragma unroll
        for (int r = 0; r < 4; r++) {
            const int row = q0 + w * 16 + lq * 4 + r;
            float* prow = po + ((size_t)pidx * 512 + row) * 64;
#pragma unroll
            for (int jd = 0; jd < 4; jd++) prow[jd * 16 + lm] = o[jd][r];
            if (lm == 0) {
                pm[pidx * 512 + row] = m_run[r];
                pl[pidx * 512 + row] = l_run[r];
            }
        }
    } else {
#pragma unroll
        for (int r = 0; r < 4; r++) {
            const float inv = 1.0f / l_run[r];
            bf16* dst = ob + (size_t)(q0 + w * 16 + lq * 4 + r) * C_ + h * HD_ + lm;
#pragma unroll
            for (int jd = 0; jd < 4; jd++) dst[jd * 16] = __float2bfloat16(o[jd][r] * inv);
        }
    }
}

// ---------------------------------------------------------------------------
// Merge 2 KV-split partials -> qh. Grid 8192 x 256 (4 rows/block).
// ---------------------------------------------------------------------------
__global__ __launch_bounds__(256)
void attn_merge(const float* __restrict__ po, const float* __restrict__ pm,
                const float* __restrict__ pl, bf16* __restrict__ qh)
{
    const int t = threadIdx.x;
    const int row = blockIdx.x * 4 + (t >> 6);   // 0..32767  (bh*512 + qr)
    const int d = t & 63;
    const int bh = row >> 9, qr = row & 511;
    const int i0 = (bh * 2) * 512 + qr, i1 = i0 + 512;
    const float m0 = pm[i0], m1 = pm[i1];
    const float l0 = pl[i0], l1 = pl[i1];
    const float nm = fmaxf(m0, m1);
    const float e0 = __expf(m0 - nm), e1 = __expf(m1 - nm);
    const float L = l0 * e0 + l1 * e1;
    const float v = (po[(size_t)i0 * 64 + d] * e0 + po[(size_t)i1 * 64 + d] * e1) / L;
    const int bb = bh >> 4, h = bh & 15;
    qh[((size_t)bb * NQ_ + qr) * C_ + h * HD_ + d] = __float2bfloat16(v);
}

// ---------------------------------------------------------------------------
static void add_job(KTr& J, const void* src, long long off, int ld,
                    bf16* dst, int K, int N)
{
    const int j = J.njobs++;
    J.src[j] = src; J.off[j] = off; J.ld[j] = ld;
    J.dst[j] = dst; J.K[j] = K; J.N[j] = N;
    J.start[j + 1] = J.start[j] + (N / 64) * (K / 64);
}

extern "C" void kernel_launch(void* const* d_in, const int* in_sizes, int n_in,
                              void* d_out, int out_size, void* d_ws, size_t ws_size,
                              hipStream_t stream)
{
    const void* query   = d_in[0];
    const void* context = d_in[1];
    const int*  mask    = (const int*)d_in[2];
    const void* Wqp = d_in[3];  const void* bqp  = d_in[4];
    const void* Wcp = d_in[5];  const void* bcp  = d_in[6];
    const void* Wq  = d_in[7];  const void* bq   = d_in[8];
    const void* Wkv = d_in[9];  const void* bkv  = d_in[10];
    const void* Wo  = d_in[11]; const void* bo   = d_in[12];
    const void* g1  = d_in[13]; const void* be1  = d_in[14];
    const void* W1  = d_in[15]; const void* bf1  = d_in[16];
    const void* W2  = d_in[17]; const void* bf2  = d_in[18];
    const void* g2  = d_in[19]; const void* be2  = d_in[20];
    const void* gf  = d_in[21]; const void* bef  = d_in[22];

    char* w = (char*)d_ws;
    const bool mega  = ws_size >= (((size_t)88 << 20) + 64);
    const bool split = ws_size >= (((size_t)110 << 20) + 64);

    float* q    = (float*)(w);
    bf16*  xn   = (bf16*) (w + ( 8u << 20));
    bf16*  qh   = (bf16*) (w + (12u << 20));
    bf16*  ff1h = (bf16*) (w + (12u << 20));
    bf16*  cbf  = (bf16*) (w + (12u << 20));
    bf16*  qbf  = (bf16*) (w + (24u << 20));
    bf16*  kb   = (bf16*) (w + (16u << 20));
    bf16*  vt   = (bf16*) (w + (32u << 20));
    bf16*  cb   = (bf16*) (w + (48u << 20));
    bf16*  Wt   = (bf16*) (w + (64u << 20));
    int*   dtf  = (int*)  (w + (mega ? (88u << 20) : (68u << 20)));
    float* po   = (float*)(w + (90u << 20));
    float* pm   = (float*)(w + (107u << 20));
    float* pl   = (float*)(w + (107u << 20) + (256u << 10));

    const int MQ = B_ * NQ_;   // 2048
    dim3 blk(256);
    const size_t M1 = 1u << 20;  // 1M bf16 elems = C_*C_

    sniff_k<<<1, blk, 0, stream>>>(query, dtf);

    // external inputs -> bf16 once
    cvt_k<<<dim3((MQ * DQ_) / 8 / 256), blk, 0, stream>>>(query, qbf, (MQ * DQ_) / 8, dtf);
    cvt_k<<<dim3((B_ * NC_ * DC_) / 8 / 256), blk, 0, stream>>>(context, cbf, (B_ * NC_ * DC_) / 8, dtf);

    // projection weight transposes (+ projections)
    bf16 *WqpT, *WcpT;
    if (mega) {
        KTr J{}; J.njobs = 0; J.start[0] = 0;
        WqpT = Wt; WcpT = Wt + M1;
        add_job(J, Wqp, 0, C_, WqpT, DQ_, C_);
        add_job(J, Wcp, 0, C_, WcpT, DC_, C_);
        tr_all<<<dim3(J.start[J.njobs]), blk, 0, stream>>>(J, dtf);
    } else {
        WqpT = WcpT = Wt;
        KTr J{}; J.njobs = 0; J.start[0] = 0;
        add_job(J, Wqp, 0, C_, Wt, DQ_, C_);
        tr_all<<<dim3(J.start[J.njobs]), blk, 0, stream>>>(J, dtf);
    }
    gemm_bf<0,0,1,64,64,64><<<dim3(C_/64, MQ/64), blk, 0, stream>>>(
        qbf, DQ_, WqpT, bqp, 0, 1.f, q, MQ, C_, DQ_, dtf);
    if (!mega) {
        KTr J{}; J.njobs = 0; J.start[0] = 0;
        add_job(J, Wcp, 0, C_, Wt, DC_, C_);
        tr_all<<<dim3(J.start[J.njobs]), blk, 0, stream>>>(J, dtf);
    }
    gemm_bf<0,0,0,128,128,32><<<dim3(C_/128, (B_*NC_)/128), blk, 0, stream>>>(
        cbf, DC_, WcpT, bcp, 0, 1.f, cb, B_*NC_, C_, DC_, dtf);

    for (int l = 0; l < 2; l++) {
        const size_t oC  = (size_t)l * C_;
        const size_t oCC = (size_t)l * C_ * C_;
        const size_t o2C = (size_t)l * 2 * C_;
        const size_t oK2 = (size_t)l * C_ * 2 * C_;
        const size_t o4C = (size_t)l * 4 * C_;
        const size_t oK4 = (size_t)l * C_ * 4 * C_;

        bf16 *WqT, *WkvT, *WoT, *W1T, *W2T;
        if (mega) {
            WqT = Wt; WkvT = Wt + M1; WoT = Wt + 3*M1; W1T = Wt + 4*M1; W2T = Wt + 8*M1;
            KTr J{}; J.njobs = 0; J.start[0] = 0;
            add_job(J, Wq,  (long long)oCC, C_,   WqT,  C_,   C_);
            add_job(J, Wkv, (long long)oK2, 2*C_, WkvT, C_,   2*C_);
            add_job(J, Wo,  (long long)oCC, C_,   WoT,  C_,   C_);
            add_job(J, W1,  (long long)oK4, 4*C_, W1T,  C_,   4*C_);
            add_job(J, W2,  (long long)oK4, C_,   W2T,  4*C_, C_);
            tr_all<<<dim3(J.start[J.njobs]), blk, 0, stream>>>(J, dtf);
        } else {
            WqT = WkvT = WoT = W1T = W2T = Wt;
        }

        // LN1 -> xn ; qh = xn @ Wq + bq
        ln_k<0><<<MQ, blk, 0, stream>>>(q, g1, be1, oC, xn, dtf);
        if (!mega) {
            KTr J{}; J.njobs = 0; J.start[0] = 0;
            add_job(J, Wq, (long long)oCC, C_, Wt, C_, C_);
            tr_all<<<dim3(J.start[J.njobs]), blk, 0, stream>>>(J, dtf);
        }
        gemm_bf<0,0,0,64,64,64><<<dim3(C_/64, MQ/64), blk, 0, stream>>>(
            xn, C_, WqT, bq, oC, 1.f, qh, MQ, C_, C_, dtf);

        // kv (all batches): K rows -> kb, V transposed -> vt
        if (!mega) {
            KTr J{}; J.njobs = 0; J.start[0] = 0;
            add_job(J, Wkv, (long long)oK2, 2*C_, Wt, C_, 2*C_);
            tr_all<<<dim3(J.start[J.njobs]), blk, 0, stream>>>(J, dtf);
        }
        gemm_kv<<<dim3((2*C_)/128, (B_*NC_)/128), blk, 0, stream>>>(
            cb, C_, WkvT, bkv, o2C, kb, vt, B_*NC_, C_, dtf);

        // attention (all batches)
        if (split) {
            attn_mfma<2><<<dim3(1024), blk, 0, stream>>>(qh, kb, vt, mask, qh, po, pm, pl);
            attn_merge<<<dim3(8192), blk, 0, stream>>>(po, pm, pl, qh);
        } else {
            attn_mfma<1><<<dim3(512), blk, 0, stream>>>(qh, kb, vt, mask, qh, po, pm, pl);
        }

        // q += qh @ Wo + bo
        if (!mega) {
            KTr J{}; J.njobs = 0; J.start[0] = 0;
            add_job(J, Wo, (long long)oCC, C_, Wt, C_, C_);
            tr_all<<<dim3(J.start[J.njobs]), blk, 0, stream>>>(J, dtf);
        }
        gemm_bf<0,1,1,64,64,64><<<dim3(C_/64, MQ/64), blk, 0, stream>>>(
            qh, C_, WoT, bo, oC, 1.f, q, MQ, C_, C_, dtf);

        // LN2 -> xn ; MLP
        ln_k<0><<<MQ, blk, 0, stream>>>(q, g2, be2, oC, xn, dtf);
        if (mega) {
            gemm_bf<1,0,0,128,64,32><<<dim3((4*C_)/64, MQ/128), blk, 0, stream>>>(
                xn, C_, W1T, bf1, o4C, 1.f, ff1h, MQ, 4*C_, C_, dtf);
            gemm_bf<0,1,1,64,64,64><<<dim3(C_/64, MQ/64), blk, 0, stream>>>(
                ff1h, 4*C_, W2T, bf2, oC, 1.f, q, MQ, C_, 4*C_, dtf);
        } else {
            for (int hf = 0; hf < 2; hf++) {
                const long long w1off = (long long)oK4 + (long long)hf * 2048;
                const long long w2off = (long long)oK4 + (long long)hf * 2048 * C_;
                {
                    KTr J{}; J.njobs = 0; J.start[0] = 0;
                    add_job(J, W1, w1off, 4*C_, Wt, C_, 2048);
                    tr_all<<<dim3(J.start[J.njobs]), blk, 0, stream>>>(J, dtf);
                }
                gemm_bf<1,0,0,128,128,32><<<dim3(2048/128, MQ/128), blk, 0, stream>>>(
                    xn, C_, Wt, bf1, o4C + hf * 2048, 1.f, ff1h, MQ, 2048, C_, dtf);
                {
                    KTr J{}; J.njobs = 0; J.start[0] = 0;
                    add_job(J, W2, w2off, C_, Wt, 2048, C_);
                    tr_all<<<dim3(J.start[J.njobs]), blk, 0, stream>>>(J, dtf);
                }
                gemm_bf<0,1,1,64,64,64><<<dim3(C_/64, MQ/64), blk, 0, stream>>>(
                    ff1h, 2048, Wt, bf2, oC, (hf == 0) ? 1.f : 0.f, q, MQ, C_, 2048, dtf);
            }
        }
    }

    ln_k<1><<<MQ, blk, 0, stream>>>(q, gf, bef, 0, d_out, dtf);
}

// Round 8
// 709.858 us; speedup vs baseline: 1.0587x; 1.0587x over previous
//
#include <hip/hip_runtime.h>
#include <hip/hip_bf16.h>
#include <math.h>

typedef __hip_bfloat16 bf16;
using short8 = __attribute__((ext_vector_type(8))) short;
using f32x4  = __attribute__((ext_vector_type(4))) float;

#define B_    4
#define NQ_   512
#define NC_   2048
#define DQ_   1024
#define DC_   768
#define C_    1024
#define H_    16
#define HD_   64
#define EPS_  1e-5f

// ---- runtime-dtyped load of EXTERNAL tensors (flag: 1=fp32, 0=bf16) ----
__device__ __forceinline__ float ldin(const void* p, size_t i, int f32) {
    return f32 ? ((const float*)p)[i]
               : __bfloat162float(((const bf16*)p)[i]);
}
__device__ __forceinline__ unsigned bfb(float f) {
    return (unsigned)__builtin_bit_cast(unsigned short, __float2bfloat16(f));
}

// async global->LDS, 16B per lane; LDS dest = wave-uniform base + lane*16
typedef const __attribute__((address_space(1))) unsigned int ga_u32;
typedef __attribute__((address_space(3))) unsigned int ls_u32;
__device__ __forceinline__ void gl16(const void* g, void* l) {
    __builtin_amdgcn_global_load_lds((ga_u32*)g, (ls_u32*)l, 16, 0, 0);
}

// ---------------------------------------------------------------------------
// dtype sniffer: flag[0] = (fp32 ? 1 : 0).
// ---------------------------------------------------------------------------
__global__ __launch_bounds__(256)
void sniff_k(const void* __restrict__ q, int* __restrict__ flag)
{
    __shared__ int red[256];
    const unsigned* w = (const unsigned*)q;
    const int t = threadIdx.x;
    int cnt = 0;
    for (int i = t; i < 1024; i += 256) {
        unsigned e = (w[i] >> 7) & 0xFFu;
        cnt += (e >= 0x70u && e <= 0x82u) ? 1 : 0;
    }
    red[t] = cnt; __syncthreads();
    for (int s = 128; s > 0; s >>= 1) { if (t < s) red[t] += red[t + s]; __syncthreads(); }
    if (t == 0) flag[0] = (red[0] > 512) ? 0 : 1;
}

// ---------------------------------------------------------------------------
// bf16 conversion (or copy) of external tensors; 8 elems/thread.
// ---------------------------------------------------------------------------
__global__ __launch_bounds__(256)
void cvt_k(const void* __restrict__ src, bf16* __restrict__ dst, int n8,
           const int* __restrict__ dtf)
{
    const int i = blockIdx.x * 256 + threadIdx.x;
    if (i >= n8) return;
    if (dtf[0]) {
        const float* s = (const float*)src + (size_t)i * 8;
        float4 a = *(const float4*)s, b = *(const float4*)(s + 4);
        uint4 o;
        o.x = bfb(a.x) | (bfb(a.y) << 16);
        o.y = bfb(a.z) | (bfb(a.w) << 16);
        o.z = bfb(b.x) | (bfb(b.y) << 16);
        o.w = bfb(b.z) | (bfb(b.w) << 16);
        *(uint4*)(dst + (size_t)i * 8) = o;
    } else {
        *(uint4*)(dst + (size_t)i * 8) = *(const uint4*)((const bf16*)src + (size_t)i * 8);
    }
}

// ---------------------------------------------------------------------------
// Batched transpose: for each job, dst[N][K] bf16 = src[off + k*ld + n]
// (runtime dtype). One launch handles up to 6 jobs via a tile table.
// ---------------------------------------------------------------------------
struct KTr {
    const void* src[6];
    bf16*       dst[6];
    long long   off[6];
    int ld[6], K[6], N[6];
    int start[7];
    int njobs;
};

__global__ __launch_bounds__(256)
void tr_all(KTr J, const int* __restrict__ dtf)
{
    __shared__ short T[64 * 65];
    const int f32 = dtf[0];
    const int t = threadIdx.x;
    int bid = blockIdx.x, j = 0;
    while (j + 1 < J.njobs && bid >= J.start[j + 1]) ++j;
    const int tt = bid - J.start[j];
    const int nx = J.N[j] >> 6;
    const int n0 = (tt % nx) * 64, k0 = (tt / nx) * 64;
    const int ld = J.ld[j], K = J.K[j];
    {
        const int k = t >> 2, nq = (t & 3) * 16;
        size_t si = (size_t)J.off[j] + (size_t)(k0 + k) * ld + n0 + nq;
        short v[16];
        if (f32) {
            const float* s = (const float*)J.src[j] + si;
#pragma unroll
            for (int u = 0; u < 4; u++) {
                float4 f = *(const float4*)(s + u * 4);
                v[u*4+0] = (short)bfb(f.x); v[u*4+1] = (short)bfb(f.y);
                v[u*4+2] = (short)bfb(f.z); v[u*4+3] = (short)bfb(f.w);
            }
        } else {
            const bf16* s = (const bf16*)J.src[j] + si;
#pragma unroll
            for (int u = 0; u < 2; u++) {
                uint4 x = *(const uint4*)(s + u * 8);
                unsigned a[4] = {x.x, x.y, x.z, x.w};
#pragma unroll
                for (int m = 0; m < 4; m++) {
                    v[u*8 + m*2]     = (short)(a[m] & 0xffffu);
                    v[u*8 + m*2 + 1] = (short)(a[m] >> 16);
                }
            }
        }
#pragma unroll
        for (int jj = 0; jj < 16; jj++) T[k * 65 + nq + jj] = v[jj];
    }
    __syncthreads();
    {
        const int n = t >> 2, kq = (t & 3) * 16;
        unsigned pk[8];
#pragma unroll
        for (int u = 0; u < 8; u++) {
            unsigned lo = (unsigned short)T[(kq + u*2)     * 65 + n];
            unsigned hi = (unsigned short)T[(kq + u*2 + 1) * 65 + n];
            pk[u] = lo | (hi << 16);
        }
        bf16* d = J.dst[j] + (size_t)(n0 + n) * K + k0 + kq;
        *(uint4*)(d)     = make_uint4(pk[0], pk[1], pk[2], pk[3]);
        *(uint4*)(d + 8) = make_uint4(pk[4], pk[5], pk[6], pk[7]);
    }
}

// ---------------------------------------------------------------------------
// Fast bf16 GEMM: out[M,N] = act(A[M,K] @ Wt[N,K]^T + bscale*bias) (+= if ACC)
// global_load_lds 16B staging (XOR-swizzled), double-buffered, 2-phase.
// Tiles: <128,128,32> (4x4), <128,64,32> (2x4), <64,64,64> (2x2, 8
// MFMA/barrier — halves barrier-drain cost for the N=1024 fleet).
// ---------------------------------------------------------------------------
template<int ACT, int ACC, int OUTF32, int BM, int BN, int BK>
__global__ __launch_bounds__(256)
void gemm_bf(const bf16* __restrict__ A, int lda,
             const bf16* __restrict__ Wt,
             const void* __restrict__ bias, size_t boff, float bscale,
             void* __restrict__ outp, int M, int N, int K,
             const int* __restrict__ dtf)
{
    __shared__ short As[2][BM * BK];
    __shared__ short Bs[2][BN * BK];
    constexpr int MI = (BM == 128 && BN == 128) ? 4 : 2;
    constexpr int NJ = (BM == 64) ? 2 : 4;
    const int t  = threadIdx.x;
    const int nwg = gridDim.x * gridDim.y;
    int flat = blockIdx.y * gridDim.x + blockIdx.x;
    flat = (flat & 7) * (nwg >> 3) + (flat >> 3);
    const int row0 = (flat / gridDim.x) * BM, col0 = (flat % gridDim.x) * BN;
    const int wv = t >> 6, l = t & 63;
    const int lm = l & 15, lq = l >> 4;
    // BK32 staging coords (4 chunks/row of 32 shorts)
    const int lr = l >> 2, lc = l & 3;
    const int swc  = lc ^ ((lr >> 1) & 3);
    const int koff = (lq ^ ((lm >> 1) & 3)) << 3;
    // BK64 staging coords (8 chunks/row of 64 shorts)
    const int lr8 = l >> 3, lc8 = l & 7;
    const int swc8 = lc8 ^ (lr8 & 7);
    const int wr = (BM == 128 && BN == 128) ? (wv >> 1) * 64
                 : (BM == 128) ? wv * 32 : (wv >> 1) * 32;
    const int wc = (BN == 128) ? (wv & 1) * 64
                 : (BM == 128) ? 0 : (wv & 1) * 32;

    const bf16* Ag0; const bf16* Ag1; const bf16* Bg0; const bf16* Bg1;
    if constexpr (BK == 64) {
        Ag0 = A + (size_t)(row0 + wv * 16 + lr8) * lda + swc8 * 8;
        Ag1 = Ag0 + (size_t)8 * lda;
        Bg0 = Wt + (size_t)(col0 + wv * 16 + lr8) * K + swc8 * 8;
        Bg1 = Bg0 + (size_t)8 * K;
    } else {
        Ag0 = A + (size_t)(row0 + ((BM == 128) ? wv * 32 : wv * 16) + lr) * lda + swc * 8;
        Ag1 = Ag0 + (size_t)16 * lda;
        Bg0 = Wt + (size_t)(col0 + ((BN == 128) ? wv * 32 : wv * 16) + lr) * K + swc * 8;
        Bg1 = Bg0 + (size_t)16 * K;
    }

    f32x4 acc[MI][NJ];
#pragma unroll
    for (int i = 0; i < MI; i++)
#pragma unroll
        for (int j = 0; j < NJ; j++) { acc[i][j][0]=0.f; acc[i][j][1]=0.f; acc[i][j][2]=0.f; acc[i][j][3]=0.f; }

    auto stage = [&](int b, int k0) {
        if constexpr (BK == 64) {
            gl16(Ag0 + k0, &As[b][(wv * 16) * 64]);
            gl16(Ag1 + k0, &As[b][(wv * 16 + 8) * 64]);
            gl16(Bg0 + k0, &Bs[b][(wv * 16) * 64]);
            gl16(Bg1 + k0, &Bs[b][(wv * 16 + 8) * 64]);
        } else {
            if constexpr (BM == 128) {
                gl16(Ag0 + k0, &As[b][(wv * 32) * 32]);
                gl16(Ag1 + k0, &As[b][(wv * 32 + 16) * 32]);
            } else {
                gl16(Ag0 + k0, &As[b][(wv * 16) * 32]);
            }
            if constexpr (BN == 128) {
                gl16(Bg0 + k0, &Bs[b][(wv * 32) * 32]);
                gl16(Bg1 + k0, &Bs[b][(wv * 32 + 16) * 32]);
            } else {
                gl16(Bg0 + k0, &Bs[b][(wv * 16) * 32]);
            }
        }
    };

    const int nt = K / BK;
    stage(0, 0);
    __syncthreads();
    int cur = 0;
    for (int tt = 0; tt < nt; ++tt) {
        if (tt + 1 < nt) stage(cur ^ 1, (tt + 1) * BK);
        if constexpr (BK == 64) {
#pragma unroll
            for (int kk = 0; kk < 2; kk++) {
                short8 af[MI], bfr[NJ];
#pragma unroll
                for (int i = 0; i < MI; i++)
                    af[i]  = *(const short8*)&As[cur][(wr + i*16 + lm) * 64 + (((kk << 2) | lq) ^ (lm & 7)) * 8];
#pragma unroll
                for (int j = 0; j < NJ; j++)
                    bfr[j] = *(const short8*)&Bs[cur][(wc + j*16 + lm) * 64 + (((kk << 2) | lq) ^ (lm & 7)) * 8];
#pragma unroll
                for (int i = 0; i < MI; i++)
#pragma unroll
                    for (int j = 0; j < NJ; j++)
                        acc[i][j] = __builtin_amdgcn_mfma_f32_16x16x32_bf16(af[i], bfr[j], acc[i][j], 0, 0, 0);
            }
        } else {
            short8 af[MI], bfr[NJ];
#pragma unroll
            for (int i = 0; i < MI; i++) af[i]  = *(const short8*)&As[cur][(wr + i*16 + lm) * 32 + koff];
#pragma unroll
            for (int j = 0; j < NJ; j++) bfr[j] = *(const short8*)&Bs[cur][(wc + j*16 + lm) * 32 + koff];
#pragma unroll
            for (int i = 0; i < MI; i++)
#pragma unroll
                for (int j = 0; j < NJ; j++)
                    acc[i][j] = __builtin_amdgcn_mfma_f32_16x16x32_bf16(af[i], bfr[j], acc[i][j], 0, 0, 0);
        }
        __syncthreads();
        cur ^= 1;
    }

    const int fb = dtf[0];
#pragma unroll
    for (int i = 0; i < MI; i++) {
#pragma unroll
        for (int j = 0; j < NJ; j++) {
            const int cgl = col0 + wc + j * 16 + lm;
            const float bsv = bscale * ldin(bias, boff + cgl, fb);
#pragma unroll
            for (int r = 0; r < 4; r++) {
                const int rgl = row0 + wr + i * 16 + lq * 4 + r;
                float v = acc[i][j][r] + bsv;
                if (ACT == 1) v = 0.5f * v * (1.0f + erff(v * 0.70710678118654752440f));
                size_t o = (size_t)rgl * N + cgl;
                if constexpr (ACC)          ((float*)outp)[o] += v;
                else if constexpr (OUTF32)  ((float*)outp)[o] = v;
                else                        ((bf16*)outp)[o] = __float2bfloat16(v);
            }
        }
    }
}

// ---------------------------------------------------------------------------
// KV GEMM: A[M,K] @ Wt[2C,K]^T + bkv. K-half cols (<C) written row-major to
// kb[b][key][C]; V-half cols transposed in LDS and written to vt[b][d][NC].
// ---------------------------------------------------------------------------
__global__ __launch_bounds__(256)
void gemm_kv(const bf16* __restrict__ A, int lda,
             const bf16* __restrict__ Wt,
             const void* __restrict__ bias, size_t boff,
             bf16* __restrict__ kb, bf16* __restrict__ vt,
             int M, int K, const int* __restrict__ dtf)
{
    __shared__ short smem[17408];          // 34816 B
    const int t  = threadIdx.x;
    const int nwg = gridDim.x * gridDim.y;
    int flat = blockIdx.y * gridDim.x + blockIdx.x;
    flat = (flat & 7) * (nwg >> 3) + (flat >> 3);
    const int row0 = (flat / gridDim.x) * 128, col0 = (flat % gridDim.x) * 128;
    const int wv = t >> 6, l = t & 63;
    const int lm = l & 15, lq = l >> 4;
    const int lr = l >> 2, lc = l & 3;
    const int swc  = lc ^ ((lr >> 1) & 3);
    const int koff = (lq ^ ((lm >> 1) & 3)) << 3;
    const int wr = (wv >> 1) * 64, wc = (wv & 1) * 64;

    const bf16* Ag0 = A + (size_t)(row0 + wv * 32 + lr) * lda + swc * 8;
    const bf16* Ag1 = Ag0 + (size_t)16 * lda;
    const bf16* Bg0 = Wt + (size_t)(col0 + wv * 32 + lr) * K + swc * 8;
    const bf16* Bg1 = Bg0 + (size_t)16 * K;

    f32x4 acc[4][4];
#pragma unroll
    for (int i = 0; i < 4; i++)
#pragma unroll
        for (int j = 0; j < 4; j++) { acc[i][j][0]=0.f; acc[i][j][1]=0.f; acc[i][j][2]=0.f; acc[i][j][3]=0.f; }

    auto stage = [&](int b, int k0) {
        gl16(Ag0 + k0, &smem[b * 4096 + (wv * 32) * 32]);
        gl16(Ag1 + k0, &smem[b * 4096 + (wv * 32 + 16) * 32]);
        gl16(Bg0 + k0, &smem[8192 + b * 4096 + (wv * 32) * 32]);
        gl16(Bg1 + k0, &smem[8192 + b * 4096 + (wv * 32 + 16) * 32]);
    };

    const int nt = K >> 5;
    stage(0, 0);
    __syncthreads();
    int cur = 0;
    for (int tt = 0; tt < nt; ++tt) {
        if (tt + 1 < nt) stage(cur ^ 1, (tt + 1) * 32);
        short8 af[4], bfr[4];
#pragma unroll
        for (int i = 0; i < 4; i++) af[i]  = *(const short8*)&smem[cur * 4096 + (wr + i*16 + lm) * 32 + koff];
#pragma unroll
        for (int j = 0; j < 4; j++) bfr[j] = *(const short8*)&smem[8192 + cur * 4096 + (wc + j*16 + lm) * 32 + koff];
#pragma unroll
        for (int i = 0; i < 4; i++)
#pragma unroll
            for (int j = 0; j < 4; j++)
                acc[i][j] = __builtin_amdgcn_mfma_f32_16x16x32_bf16(af[i], bfr[j], acc[i][j], 0, 0, 0);
        __syncthreads();
        cur ^= 1;
    }

    const int fb = dtf[0];
    if (col0 < C_) {
#pragma unroll
        for (int i = 0; i < 4; i++)
#pragma unroll
            for (int j = 0; j < 4; j++) {
                const int cgl = col0 + wc + j * 16 + lm;
                const float bsv = ldin(bias, boff + cgl, fb);
#pragma unroll
                for (int r = 0; r < 4; r++) {
                    const int rgl = row0 + wr + i * 16 + lq * 4 + r;
                    kb[(size_t)rgl * C_ + cgl] = __float2bfloat16(acc[i][j][r] + bsv);
                }
            }
    } else {
#pragma unroll
        for (int i = 0; i < 4; i++)
#pragma unroll
            for (int j = 0; j < 4; j++) {
                const int cl = wc + j * 16 + lm;
                const float bsv = ldin(bias, boff + col0 + cl, fb);
                unsigned p0 = bfb(acc[i][j][0] + bsv) | (bfb(acc[i][j][1] + bsv) << 16);
                unsigned p1 = bfb(acc[i][j][2] + bsv) | (bfb(acc[i][j][3] + bsv) << 16);
                *(uint2*)&smem[cl * 136 + wr + i * 16 + lq * 4] = make_uint2(p0, p1);
            }
        __syncthreads();
        const int dr = t >> 1, half = (t & 1) * 64;
        const int b = row0 >> 11, key0 = row0 & (NC_ - 1);
        bf16* dst = vt + (size_t)b * C_ * NC_ + (size_t)(col0 - C_ + dr) * NC_ + key0 + half;
#pragma unroll
        for (int u = 0; u < 8; u++)
            *(uint4*)(dst + u * 8) = *(const uint4*)&smem[dr * 136 + half + u * 8];
    }
}

// ---------------------------------------------------------------------------
// LayerNorm (C_=1024).
// ---------------------------------------------------------------------------
template<int OFINAL>
__global__ __launch_bounds__(256)
void ln_k(const float* __restrict__ x, const void* __restrict__ g,
          const void* __restrict__ b, size_t gboff, void* __restrict__ out,
          const int* __restrict__ dtf)
{
    __shared__ float red[256];
    const int f32 = dtf[0];
    const int row = blockIdx.x;
    const int t = threadIdx.x;
    const float* xr = x + (size_t)row * C_;
    float v[4];
#pragma unroll
    for (int i = 0; i < 4; i++) v[i] = xr[t + 256 * i];
    float s = v[0] + v[1] + v[2] + v[3];
    red[t] = s; __syncthreads();
    for (int st = 128; st > 0; st >>= 1) { if (t < st) red[t] += red[t + st]; __syncthreads(); }
    float mean = red[0] * (1.0f / C_);
    __syncthreads();
    float s2 = 0.f;
#pragma unroll
    for (int i = 0; i < 4; i++) { float d = v[i] - mean; s2 += d * d; }
    red[t] = s2; __syncthreads();
    for (int st = 128; st > 0; st >>= 1) { if (t < st) red[t] += red[t + st]; __syncthreads(); }
    float rstd = rsqrtf(red[0] * (1.0f / C_) + EPS_);
#pragma unroll
    for (int i = 0; i < 4; i++) {
        int cc = t + 256 * i;
        float r = (v[i] - mean) * rstd * ldin(g, gboff + cc, f32) + ldin(b, gboff + cc, f32);
        size_t o = (size_t)row * C_ + cc;
        if constexpr (OFINAL) {
            if (f32) ((float*)out)[o] = r; else ((bf16*)out)[o] = __float2bfloat16(r);
        } else {
            ((bf16*)out)[o] = __float2bfloat16(r);
        }
    }
}

// ---------------------------------------------------------------------------
// MFMA flash attention, KVBLK=128 (the twice-measured 61.x µs version:
// cndmask masking, unconditional rescale, P stride 136, VGPR 80).
// NSPLIT=2: grid 1024, partials (po,pm,pl) + attn_merge.
// ---------------------------------------------------------------------------
template<int NSPLIT>
__global__ __launch_bounds__(256)
void attn_mfma(const bf16* __restrict__ qh, const bf16* __restrict__ kb,
               const bf16* __restrict__ vt, const int* __restrict__ mask,
               bf16* __restrict__ out,
               float* __restrict__ po, float* __restrict__ pm,
               float* __restrict__ pl)
{
    __shared__ short Ks[128 * 72];     // [key][d]
    __shared__ short Vs[64 * 136];     // [d][key]
    __shared__ short Ps[4][16 * 136];  // per-wave P [q][key]

    const int id = blockIdx.x;
    const int xcd = id & 7, kk = id >> 3;
    const int p = xcd + ((kk >> 3) << 3);
    int bb, h, sp;
    if constexpr (NSPLIT == 2) { bb = p >> 5; h = (p >> 1) & 15; sp = p & 1; }
    else                       { bb = p >> 4; h = p & 15;        sp = 0;     }
    const int q0 = (kk & 7) * 64;
    const int kbase = sp * (NC_ / NSPLIT);
    const int klen  = NC_ / NSPLIT;

    const bf16* qhb = qh + (size_t)bb * NQ_ * C_;
    const bf16* kbb = kb + (size_t)bb * NC_ * C_;
    const bf16* vtb = vt + (size_t)bb * C_ * NC_ + (size_t)h * HD_ * NC_;
    const int*  mb  = mask + bb * NC_ + kbase;
    bf16* ob = out + (size_t)bb * NQ_ * C_;

    const int t  = threadIdx.x;
    const int w  = t >> 6, l = t & 63;
    const int lm = l & 15, lq = l >> 4;
    short* Pw = Ps[w];

    short8 qf[2];
    {
        const bf16* qp = qhb + (size_t)(q0 + w * 16 + lm) * C_ + h * HD_ + lq * 8;
        qf[0] = *(const short8*)(qp);
        qf[1] = *(const short8*)(qp + 32);
    }

    f32x4 o[4];
#pragma unroll
    for (int jd = 0; jd < 4; jd++) { o[jd][0]=0.f; o[jd][1]=0.f; o[jd][2]=0.f; o[jd][3]=0.f; }
    float m_run[4], l_run[4];
#pragma unroll
    for (int r = 0; r < 4; r++) { m_run[r] = -1e30f; l_run[r] = 0.f; }

    const int kr4 = t >> 2;                    // 0..63
    const int c16 = (t & 3) * 16;              // K col chunk (shorts)
    const int c32 = (t & 3) * 32;              // V key chunk (shorts)
    const bf16* kg = kbb + (size_t)(kbase + kr4) * C_ + h * HD_ + c16;
    const bf16* vg = vtb + (size_t)kr4 * NC_ + kbase + c32;

    uint4 k00, k01, k10, k11, v0, v1, v2, v3;
    int mk[8];
    {
        k00 = *(const uint4*)(kg);
        k01 = *(const uint4*)(kg + 8);
        k10 = *(const uint4*)(kg + (size_t)64 * C_);
        k11 = *(const uint4*)(kg + (size_t)64 * C_ + 8);
        v0  = *(const uint4*)(vg);
        v1  = *(const uint4*)(vg + 8);
        v2  = *(const uint4*)(vg + 16);
        v3  = *(const uint4*)(vg + 24);
#pragma unroll
        for (int jt = 0; jt < 8; jt++) mk[jt] = mb[jt * 16 + lm];
    }

    for (int k0 = 0; k0 < klen; k0 += 128) {
        __syncthreads();   // previous tile's LDS reads complete
        *(uint4*)&Ks[kr4 * 72 + c16]            = k00;
        *(uint4*)&Ks[kr4 * 72 + c16 + 8]        = k01;
        *(uint4*)&Ks[(kr4 + 64) * 72 + c16]     = k10;
        *(uint4*)&Ks[(kr4 + 64) * 72 + c16 + 8] = k11;
        *(uint4*)&Vs[kr4 * 136 + c32]      = v0;
        *(uint4*)&Vs[kr4 * 136 + c32 + 8]  = v1;
        *(uint4*)&Vs[kr4 * 136 + c32 + 16] = v2;
        *(uint4*)&Vs[kr4 * 136 + c32 + 24] = v3;
        int mc[8];
#pragma unroll
        for (int jt = 0; jt < 8; jt++) mc[jt] = mk[jt];
        __syncthreads();

        if (k0 + 128 < klen) {
            const bf16* kp = kg + (size_t)(k0 + 128) * C_;
            k00 = *(const uint4*)(kp);
            k01 = *(const uint4*)(kp + 8);
            k10 = *(const uint4*)(kp + (size_t)64 * C_);
            k11 = *(const uint4*)(kp + (size_t)64 * C_ + 8);
            const bf16* vp = vg + k0 + 128;
            v0 = *(const uint4*)(vp);
            v1 = *(const uint4*)(vp + 8);
            v2 = *(const uint4*)(vp + 16);
            v3 = *(const uint4*)(vp + 24);
#pragma unroll
            for (int jt = 0; jt < 8; jt++) mk[jt] = mb[k0 + 128 + jt * 16 + lm];
        }

        // S = Q @ K^T : 8 key-tiles x 2 d-chunks
        f32x4 s[8];
#pragma unroll
        for (int jt = 0; jt < 8; jt++) { s[jt][0]=0.f; s[jt][1]=0.f; s[jt][2]=0.f; s[jt][3]=0.f; }
        __builtin_amdgcn_s_setprio(1);
#pragma unroll
        for (int dc = 0; dc < 2; dc++) {
#pragma unroll
            for (int jt = 0; jt < 8; jt++) {
                short8 kf = *(const short8*)&Ks[(jt * 16 + lm) * 72 + dc * 32 + lq * 8];
                s[jt] = __builtin_amdgcn_mfma_f32_16x16x32_bf16(qf[dc], kf, s[jt], 0, 0, 0);
            }
        }
        __builtin_amdgcn_s_setprio(0);
#pragma unroll
        for (int jt = 0; jt < 8; jt++) {
#pragma unroll
            for (int r = 0; r < 4; r++)
                s[jt][r] = mc[jt] ? s[jt][r] * 0.125f : -1e30f;
        }

        // online softmax per row; rows live in 16-lane groups (lq fixed)
#pragma unroll
        for (int r = 0; r < 4; r++) {
            float mt = fmaxf(fmaxf(fmaxf(s[0][r], s[1][r]), fmaxf(s[2][r], s[3][r])),
                             fmaxf(fmaxf(s[4][r], s[5][r]), fmaxf(s[6][r], s[7][r])));
#pragma unroll
            for (int sh = 1; sh < 16; sh <<= 1) mt = fmaxf(mt, __shfl_xor(mt, sh, 64));
            const float nm = fmaxf(m_run[r], mt);
            const float al = __expf(m_run[r] - nm);
            float rs = 0.f;
            short* pr = &Pw[(lq * 4 + r) * 136 + lm];
#pragma unroll
            for (int jt = 0; jt < 8; jt++) {
                float pv = __expf(s[jt][r] - nm);
                pr[jt * 16] = (short)bfb(pv);
                rs += pv;
            }
#pragma unroll
            for (int sh = 1; sh < 16; sh <<= 1) rs += __shfl_xor(rs, sh, 64);
            l_run[r] = l_run[r] * al + rs;
            m_run[r] = nm;
#pragma unroll
            for (int jd = 0; jd < 4; jd++) o[jd][r] *= al;
        }

        // PV: A = P[q][key] (per-wave LDS), B = V^T[d][key]
        short8 pa[4];
#pragma unroll
        for (int c = 0; c < 4; c++) pa[c] = *(const short8*)&Pw[lm * 136 + c * 32 + lq * 8];
        __builtin_amdgcn_s_setprio(1);
#pragma unroll
        for (int jd = 0; jd < 4; jd++) {
#pragma unroll
            for (int c = 0; c < 4; c++) {
                short8 vf = *(const short8*)&Vs[(jd * 16 + lm) * 136 + c * 32 + lq * 8];
                o[jd] = __builtin_amdgcn_mfma_f32_16x16x32_bf16(pa[c], vf, o[jd], 0, 0, 0);
            }
        }
        __builtin_amdgcn_s_setprio(0);
    }

    if constexpr (NSPLIT == 2) {
        const int pidx = ((bb * 16 + h) * 2 + sp);
#pragma unroll
        for (int r = 0; r < 4; r++) {
            const int row = q0 + w * 16 + lq * 4 + r;
            float* prow = po + ((size_t)pidx * 512 + row) * 64;
#pragma unroll
            for (int jd = 0; jd < 4; jd++) prow[jd * 16 + lm] = o[jd][r];
            if (lm == 0) {
                pm[pidx * 512 + row] = m_run[r];
                pl[pidx * 512 + row] = l_run[r];
            }
        }
    } else {
#pragma unroll
        for (int r = 0; r < 4; r++) {
            const float inv = 1.0f / l_run[r];
            bf16* dst = ob + (size_t)(q0 + w * 16 + lq * 4 + r) * C_ + h * HD_ + lm;
#pragma unroll
            for (int jd = 0; jd < 4; jd++) dst[jd * 16] = __float2bfloat16(o[jd][r] * inv);
        }
    }
}

// ---------------------------------------------------------------------------
// Merge 2 KV-split partials -> qh. Grid 8192 x 256 (4 rows/block).
// ---------------------------------------------------------------------------
__global__ __launch_bounds__(256)
void attn_merge(const float* __restrict__ po, const float* __restrict__ pm,
                const float* __restrict__ pl, bf16* __restrict__ qh)
{
    const int t = threadIdx.x;
    const int row = blockIdx.x * 4 + (t >> 6);   // 0..32767  (bh*512 + qr)
    const int d = t & 63;
    const int bh = row >> 9, qr = row & 511;
    const int i0 = (bh * 2) * 512 + qr, i1 = i0 + 512;
    const float m0 = pm[i0], m1 = pm[i1];
    const float l0 = pl[i0], l1 = pl[i1];
    const float nm = fmaxf(m0, m1);
    const float e0 = __expf(m0 - nm), e1 = __expf(m1 - nm);
    const float L = l0 * e0 + l1 * e1;
    const float v = (po[(size_t)i0 * 64 + d] * e0 + po[(size_t)i1 * 64 + d] * e1) / L;
    const int bb = bh >> 4, h = bh & 15;
    qh[((size_t)bb * NQ_ + qr) * C_ + h * HD_ + d] = __float2bfloat16(v);
}

// ---------------------------------------------------------------------------
static void add_job(KTr& J, const void* src, long long off, int ld,
                    bf16* dst, int K, int N)
{
    const int j = J.njobs++;
    J.src[j] = src; J.off[j] = off; J.ld[j] = ld;
    J.dst[j] = dst; J.K[j] = K; J.N[j] = N;
    J.start[j + 1] = J.start[j] + (N / 64) * (K / 64);
}

extern "C" void kernel_launch(void* const* d_in, const int* in_sizes, int n_in,
                              void* d_out, int out_size, void* d_ws, size_t ws_size,
                              hipStream_t stream)
{
    const void* query   = d_in[0];
    const void* context = d_in[1];
    const int*  mask    = (const int*)d_in[2];
    const void* Wqp = d_in[3];  const void* bqp  = d_in[4];
    const void* Wcp = d_in[5];  const void* bcp  = d_in[6];
    const void* Wq  = d_in[7];  const void* bq   = d_in[8];
    const void* Wkv = d_in[9];  const void* bkv  = d_in[10];
    const void* Wo  = d_in[11]; const void* bo   = d_in[12];
    const void* g1  = d_in[13]; const void* be1  = d_in[14];
    const void* W1  = d_in[15]; const void* bf1  = d_in[16];
    const void* W2  = d_in[17]; const void* bf2  = d_in[18];
    const void* g2  = d_in[19]; const void* be2  = d_in[20];
    const void* gf  = d_in[21]; const void* bef  = d_in[22];

    char* w = (char*)d_ws;
    const bool mega  = ws_size >= (((size_t)88 << 20) + 64);
    const bool split = ws_size >= (((size_t)110 << 20) + 64);

    float* q    = (float*)(w);
    bf16*  xn   = (bf16*) (w + ( 8u << 20));
    bf16*  qh   = (bf16*) (w + (12u << 20));
    bf16*  ff1h = (bf16*) (w + (12u << 20));
    bf16*  cbf  = (bf16*) (w + (12u << 20));
    bf16*  qbf  = (bf16*) (w + (24u << 20));
    bf16*  kb   = (bf16*) (w + (16u << 20));
    bf16*  vt   = (bf16*) (w + (32u << 20));
    bf16*  cb   = (bf16*) (w + (48u << 20));
    bf16*  Wt   = (bf16*) (w + (64u << 20));
    int*   dtf  = (int*)  (w + (mega ? (88u << 20) : (68u << 20)));
    float* po   = (float*)(w + (90u << 20));
    float* pm   = (float*)(w + (107u << 20));
    float* pl   = (float*)(w + (107u << 20) + (256u << 10));

    const int MQ = B_ * NQ_;   // 2048
    dim3 blk(256);
    const size_t M1 = 1u << 20;  // 1M bf16 elems = C_*C_

    sniff_k<<<1, blk, 0, stream>>>(query, dtf);

    // external inputs -> bf16 once
    cvt_k<<<dim3((MQ * DQ_) / 8 / 256), blk, 0, stream>>>(query, qbf, (MQ * DQ_) / 8, dtf);
    cvt_k<<<dim3((B_ * NC_ * DC_) / 8 / 256), blk, 0, stream>>>(context, cbf, (B_ * NC_ * DC_) / 8, dtf);

    // projection weight transposes (+ projections)
    bf16 *WqpT, *WcpT;
    if (mega) {
        KTr J{}; J.njobs = 0; J.start[0] = 0;
        WqpT = Wt; WcpT = Wt + M1;
        add_job(J, Wqp, 0, C_, WqpT, DQ_, C_);
        add_job(J, Wcp, 0, C_, WcpT, DC_, C_);
        tr_all<<<dim3(J.start[J.njobs]), blk, 0, stream>>>(J, dtf);
    } else {
        WqpT = WcpT = Wt;
        KTr J{}; J.njobs = 0; J.start[0] = 0;
        add_job(J, Wqp, 0, C_, Wt, DQ_, C_);
        tr_all<<<dim3(J.start[J.njobs]), blk, 0, stream>>>(J, dtf);
    }
    gemm_bf<0,0,1,64,64,64><<<dim3(C_/64, MQ/64), blk, 0, stream>>>(
        qbf, DQ_, WqpT, bqp, 0, 1.f, q, MQ, C_, DQ_, dtf);
    if (!mega) {
        KTr J{}; J.njobs = 0; J.start[0] = 0;
        add_job(J, Wcp, 0, C_, Wt, DC_, C_);
        tr_all<<<dim3(J.start[J.njobs]), blk, 0, stream>>>(J, dtf);
    }
    gemm_bf<0,0,0,128,128,32><<<dim3(C_/128, (B_*NC_)/128), blk, 0, stream>>>(
        cbf, DC_, WcpT, bcp, 0, 1.f, cb, B_*NC_, C_, DC_, dtf);

    for (int l = 0; l < 2; l++) {
        const size_t oC  = (size_t)l * C_;
        const size_t oCC = (size_t)l * C_ * C_;
        const size_t o2C = (size_t)l * 2 * C_;
        const size_t oK2 = (size_t)l * C_ * 2 * C_;
        const size_t o4C = (size_t)l * 4 * C_;
        const size_t oK4 = (size_t)l * C_ * 4 * C_;

        bf16 *WqT, *WkvT, *WoT, *W1T, *W2T;
        if (mega) {
            WqT = Wt; WkvT = Wt + M1; WoT = Wt + 3*M1; W1T = Wt + 4*M1; W2T = Wt + 8*M1;
            KTr J{}; J.njobs = 0; J.start[0] = 0;
            add_job(J, Wq,  (long long)oCC, C_,   WqT,  C_,   C_);
            add_job(J, Wkv, (long long)oK2, 2*C_, WkvT, C_,   2*C_);
            add_job(J, Wo,  (long long)oCC, C_,   WoT,  C_,   C_);
            add_job(J, W1,  (long long)oK4, 4*C_, W1T,  C_,   4*C_);
            add_job(J, W2,  (long long)oK4, C_,   W2T,  4*C_, C_);
            tr_all<<<dim3(J.start[J.njobs]), blk, 0, stream>>>(J, dtf);
        } else {
            WqT = WkvT = WoT = W1T = W2T = Wt;
        }

        // LN1 -> xn ; qh = xn @ Wq + bq
        ln_k<0><<<MQ, blk, 0, stream>>>(q, g1, be1, oC, xn, dtf);
        if (!mega) {
            KTr J{}; J.njobs = 0; J.start[0] = 0;
            add_job(J, Wq, (long long)oCC, C_, Wt, C_, C_);
            tr_all<<<dim3(J.start[J.njobs]), blk, 0, stream>>>(J, dtf);
        }
        gemm_bf<0,0,0,64,64,64><<<dim3(C_/64, MQ/64), blk, 0, stream>>>(
            xn, C_, WqT, bq, oC, 1.f, qh, MQ, C_, C_, dtf);

        // kv (all batches): K rows -> kb, V transposed -> vt
        if (!mega) {
            KTr J{}; J.njobs = 0; J.start[0] = 0;
            add_job(J, Wkv, (long long)oK2, 2*C_, Wt, C_, 2*C_);
            tr_all<<<dim3(J.start[J.njobs]), blk, 0, stream>>>(J, dtf);
        }
        gemm_kv<<<dim3((2*C_)/128, (B_*NC_)/128), blk, 0, stream>>>(
            cb, C_, WkvT, bkv, o2C, kb, vt, B_*NC_, C_, dtf);

        // attention (all batches)
        if (split) {
            attn_mfma<2><<<dim3(1024), blk, 0, stream>>>(qh, kb, vt, mask, qh, po, pm, pl);
            attn_merge<<<dim3(8192), blk, 0, stream>>>(po, pm, pl, qh);
        } else {
            attn_mfma<1><<<dim3(512), blk, 0, stream>>>(qh, kb, vt, mask, qh, po, pm, pl);
        }

        // q += qh @ Wo + bo
        if (!mega) {
            KTr J{}; J.njobs = 0; J.start[0] = 0;
            add_job(J, Wo, (long long)oCC, C_, Wt, C_, C_);
            tr_all<<<dim3(J.start[J.njobs]), blk, 0, stream>>>(J, dtf);
        }
        gemm_bf<0,1,1,64,64,64><<<dim3(C_/64, MQ/64), blk, 0, stream>>>(
            qh, C_, WoT, bo, oC, 1.f, q, MQ, C_, C_, dtf);

        // LN2 -> xn ; MLP
        ln_k<0><<<MQ, blk, 0, stream>>>(q, g2, be2, oC, xn, dtf);
        if (mega) {
            gemm_bf<1,0,0,128,64,32><<<dim3((4*C_)/64, MQ/128), blk, 0, stream>>>(
                xn, C_, W1T, bf1, o4C, 1.f, ff1h, MQ, 4*C_, C_, dtf);
            gemm_bf<0,1,1,64,64,64><<<dim3(C_/64, MQ/64), blk, 0, stream>>>(
                ff1h, 4*C_, W2T, bf2, oC, 1.f, q, MQ, C_, 4*C_, dtf);
        } else {
            for (int hf = 0; hf < 2; hf++) {
                const long long w1off = (long long)oK4 + (long long)hf * 2048;
                const long long w2off = (long long)oK4 + (long long)hf * 2048 * C_;
                {
                    KTr J{}; J.njobs = 0; J.start[0] = 0;
                    add_job(J, W1, w1off, 4*C_, Wt, C_, 2048);
                    tr_all<<<dim3(J.start[J.njobs]), blk, 0, stream>>>(J, dtf);
                }
                gemm_bf<1,0,0,128,128,32><<<dim3(2048/128, MQ/128), blk, 0, stream>>>(
                    xn, C_, Wt, bf1, o4C + hf * 2048, 1.f, ff1h, MQ, 2048, C_, dtf);
                {
                    KTr J{}; J.njobs = 0; J.start[0] = 0;
                    add_job(J, W2, w2off, C_, Wt, 2048, C_);
                    tr_all<<<dim3(J.start[J.njobs]), blk, 0, stream>>>(J, dtf);
                }
                gemm_bf<0,1,1,64,64,64><<<dim3(C_/64, MQ/64), blk, 0, stream>>>(
                    ff1h, 2048, Wt, bf2, oC, (hf == 0) ? 1.f : 0.f, q, MQ, C_, 2048, dtf);
            }
        }
    }

    ln_k<1><<<MQ, blk, 0, stream>>>(q, gf, bef, 0, d_out, dtf);
}